// Round 2
// baseline (313.857 us; speedup 1.0000x reference)
//
#include <hip/hip_runtime.h>

typedef __bf16 bf16;
typedef __bf16 bf16x2 __attribute__((ext_vector_type(2)));
typedef __bf16 bf16x4 __attribute__((ext_vector_type(4)));
typedef __bf16 bf16x8 __attribute__((ext_vector_type(8)));
typedef float f32x4 __attribute__((ext_vector_type(4)));

#define MFMA(a, b, c) __builtin_amdgcn_mfma_f32_16x16x32_bf16(a, b, c, 0, 0, 0)

#define GLD16(gptr, ldsptr)                                                        \
  __builtin_amdgcn_global_load_lds(                                                \
      (const __attribute__((address_space(1))) unsigned int*)(gptr),               \
      (__attribute__((address_space(3))) unsigned int*)(ldsptr), 16, 0, 0)

union I4B8 { int4 i; bf16x8 v; };
union HI { bf16x2 h; int i; };

// ---------------- fused cast (x, ctx) + weight transposes, one dispatch ----------------
// Wq is additionally scaled by 0.125*log2(e) so attention can use raw exp2.
__global__ __launch_bounds__(256) void prep_k(const float* __restrict__ x, bf16* __restrict__ xb,
                                              const float* __restrict__ ctx, bf16* __restrict__ ctxb,
                                              const float* __restrict__ Wq, bf16* __restrict__ WqT,
                                              const float* __restrict__ Wk, bf16* __restrict__ WkvT,
                                              const float* __restrict__ Wv,
                                              const float* __restrict__ Wo, bf16* __restrict__ WoT) {
  __shared__ float t[32][33];
  const int bid = blockIdx.x;
  if (bid < 5632) {  // casts
    const float* in; bf16* out; size_t i;
    if (bid < 4096) { in = x; out = xb; i = ((size_t)bid * 256 + threadIdx.x) * 8; }
    else { in = ctx; out = ctxb; i = ((size_t)(bid - 4096) * 256 + threadIdx.x) * 8; }
    const float4 a = *(const float4*)(in + i);
    const float4 b = *(const float4*)(in + i + 4);
    bf16x8 o;
    o[0] = (bf16)a.x; o[1] = (bf16)a.y; o[2] = (bf16)a.z; o[3] = (bf16)a.w;
    o[4] = (bf16)b.x; o[5] = (bf16)b.y; o[6] = (bf16)b.z; o[7] = (bf16)b.w;
    *(bf16x8*)(out + i) = o;
    return;
  }
  // transposes: out[C][R] = (bf16)(in[R][C] * sc)
  const int tt = bid - 5632;
  const int z = tt >> 10, rem = tt & 1023;
  const float* in; bf16* out; int R; float sc = 1.0f;
  if (z == 0)      { in = Wq; out = WqT;                R = 1024; sc = 0.18033688f; }
  else if (z == 1) { in = Wk; out = WkvT;               R = 768; }
  else if (z == 2) { in = Wv; out = WkvT + 1024 * 768;  R = 768; }
  else             { in = Wo; out = WoT;                R = 1024; }
  const int c0 = (rem & 31) * 32, r0 = (rem >> 5) * 32;
  if (r0 >= R) return;
  const int tx = threadIdx.x & 31, ty = threadIdx.x >> 5;
#pragma unroll
  for (int i = 0; i < 4; i++)
    t[ty + i * 8][tx] = in[(size_t)(r0 + ty + i * 8) * 1024 + c0 + tx];
  __syncthreads();
#pragma unroll
  for (int i = 0; i < 4; i++)
    out[(size_t)(c0 + ty + i * 8) * R + r0 + tx] = (bf16)(t[tx][ty + i * 8] * sc);
}

// ---------------- GEMM body: C[M,N] = A[M,K] @ Bt[N,K]^T ----------------
// 128x128 tile, BK=64, XOR-swizzled LDS (st-style: elem col ^= (row&7)*8) so the
// 128B-stride ds_read_b128 is conflict-free. global_load_lds writes LINEARLY, so
// the swizzle is applied by pre-swizzling the per-lane GLOBAL source column
// (both-sides-or-neither, m201/m173). Half the barriers of the BK=32 structure.
// MODE 0: SWAPPED (C^T frags) -> bf16 rowmajor ld=1024, b64 stores.
// MODE 1: SWAPPED -> fp32 rowmajor ld=1024 + bias, dwordx4 stores.
// MODE 2: NORMAL  -> V^T [B,H,64,1024] with sigma key-permute, b64 stores.
template <int MODE>
__device__ __forceinline__ void gemm_body(const bf16* __restrict__ A,
                                          const bf16* __restrict__ Bt,
                                          int K, int m0, int n0,
                                          void* __restrict__ C0,
                                          const float* __restrict__ bias,
                                          bf16* As, bf16* Bs) {
  const int tid = threadIdx.x;
  const int lane = tid & 63, wave = tid >> 6;
  const int wm = wave >> 1, wn = wave & 1;
  const int q = lane >> 4, c = lane & 15;

  f32x4 acc[4][4] = {};
  // staging: thread t -> row r = t>>3 (+32 per call), 16B at swizzled col
  const int r = tid >> 3;
  const int col8 = ((tid & 7) * 8) ^ ((r & 7) * 8);
  const bf16* Ag = A + (size_t)(m0 + r) * K + col8;
  const bf16* Bg = Bt + (size_t)(n0 + r) * K + col8;
  const size_t K32 = (size_t)K * 32;
  bf16* AsW = As + wave * 512;   // call j writes As + j*2048 + wave*512
  bf16* BsW = Bs + wave * 512;
  const int swz = (c & 7) * 8;   // read-side XOR (row&7 == c&7 for frag rows)

  for (int k0 = 0; k0 < K; k0 += 64) {
    __syncthreads();
    GLD16(Ag + k0,            AsW);
    GLD16(Ag + k0 + K32,      AsW + 2048);
    GLD16(Ag + k0 + 2 * K32,  AsW + 4096);
    GLD16(Ag + k0 + 3 * K32,  AsW + 6144);
    GLD16(Bg + k0,            BsW);
    GLD16(Bg + k0 + K32,      BsW + 2048);
    GLD16(Bg + k0 + 2 * K32,  BsW + 4096);
    GLD16(Bg + k0 + 3 * K32,  BsW + 6144);
    __syncthreads();
#pragma unroll
    for (int kk = 0; kk < 2; kk++) {
      const int cx = (kk * 32 + q * 8) ^ swz;
      bf16x8 af[4], bfr[4];
#pragma unroll
      for (int mi = 0; mi < 4; mi++)
        af[mi] = *(const bf16x8*)&As[(wm * 64 + mi * 16 + c) * 64 + cx];
#pragma unroll
      for (int ni = 0; ni < 4; ni++)
        bfr[ni] = *(const bf16x8*)&Bs[(wn * 64 + ni * 16 + c) * 64 + cx];
      __builtin_amdgcn_s_setprio(1);
#pragma unroll
      for (int mi = 0; mi < 4; mi++)
#pragma unroll
        for (int ni = 0; ni < 4; ni++) {
          if constexpr (MODE == 2)
            acc[mi][ni] = MFMA(af[mi], bfr[ni], acc[mi][ni]);   // D[m][n]
          else
            acc[mi][ni] = MFMA(bfr[ni], af[mi], acc[mi][ni]);   // D[n][m]
        }
      __builtin_amdgcn_s_setprio(0);
    }
  }

  if constexpr (MODE == 0 || MODE == 1) {
    // swapped: lane (q,c) of acc[mi][ni] holds row m0+wm*64+mi*16+c,
    // cols n0+wn*64+ni*16+q*4 .. +3
#pragma unroll
    for (int ni = 0; ni < 4; ni++) {
      const int col = n0 + wn * 64 + ni * 16 + q * 4;
      float4 bv4 = {};
      if constexpr (MODE == 1) bv4 = *(const float4*)&bias[col];
#pragma unroll
      for (int mi = 0; mi < 4; mi++) {
        const int row = m0 + wm * 64 + mi * 16 + c;
        if constexpr (MODE == 0) {
          bf16x4 vv;
#pragma unroll
          for (int r2 = 0; r2 < 4; r2++) vv[r2] = (bf16)acc[mi][ni][r2];
          *(bf16x4*)&((bf16*)C0)[(size_t)row * 1024 + col] = vv;
        } else {
          f32x4 vv;
          vv[0] = acc[mi][ni][0] + bv4.x; vv[1] = acc[mi][ni][1] + bv4.y;
          vv[2] = acc[mi][ni][2] + bv4.z; vv[3] = acc[mi][ni][3] + bv4.w;
          *(f32x4*)&((float*)C0)[(size_t)row * 1024 + col] = vv;
        }
      }
    }
  } else {
    // normal: lane (q,c) of acc[mi][ni] holds rows rbase+q*4..+3 (keys), col fixed.
#pragma unroll
    for (int ni = 0; ni < 4; ni++) {
      const int col = n0 + wn * 64 + ni * 16 + c;
#pragma unroll
      for (int mi = 0; mi < 4; mi++) {
        const int rbase = m0 + wm * 64 + mi * 16 + q * 4;
        const int b = rbase >> 10, key = rbase & 1023;
        bf16* VT = (bf16*)C0;
        const int h = col >> 6, d = col & 63;
        const int kl = key & 63;
        const int pkey = (key & ~63) | (kl & 32) | ((kl & 12) << 1) | ((kl & 16) >> 2);
        bf16x4 vv;
#pragma unroll
        for (int r2 = 0; r2 < 4; r2++) vv[r2] = (bf16)acc[mi][ni][r2];
        *(bf16x4*)&VT[((size_t)(b * 16 + h) * 64 + d) * 1024 + pkey] = vv;
      }
    }
  }
}

// ---------------- fused Q-proj + K-proj + V-proj, 1024 blocks ----------------
// XCD chunk-swizzle per segment: each XCD owns a contiguous band of row-tiles.
__global__ __launch_bounds__(256) void proj_k(const bf16* __restrict__ xb,
                                              const bf16* __restrict__ ctxb,
                                              const bf16* __restrict__ WqT,
                                              const bf16* __restrict__ WkvT,
                                              bf16* __restrict__ Q,
                                              bf16* __restrict__ Kp,
                                              bf16* __restrict__ VT) {
  __shared__ __align__(16) bf16 As[8192];
  __shared__ __align__(16) bf16 Bs[8192];
  const int bid = blockIdx.x;
  if (bid < 512) {        // Q projection: M=8192, N=1024, K=1024, bf16 swapped
    const int s = (bid & 7) * 64 + (bid >> 3);
    gemm_body<0>(xb, WqT, 1024, (s >> 3) * 128, (s & 7) * 128, Q, nullptr, As, Bs);
  } else if (bid < 768) { // K projection: M=4096, N=1024, K=768, bf16 swapped
    const int t = bid - 512;
    const int s = (t & 7) * 32 + (t >> 3);
    gemm_body<0>(ctxb, WkvT, 768, (s >> 3) * 128, (s & 7) * 128, Kp, nullptr, As, Bs);
  } else {                // V projection: M=4096, N=1024, K=768, normal -> sigma V^T
    const int t = bid - 768;
    const int s = (t & 7) * 32 + (t >> 3);
    gemm_body<2>(ctxb, WkvT + (size_t)1024 * 768, 768, (s >> 3) * 128, (s & 7) * 128,
                 VT, nullptr, As, Bs);
  }
}

// ---------------- output projection, fp32 + bias, 128x128 tiles (512 blocks) ----------------
__global__ __launch_bounds__(256) void out_k(const bf16* __restrict__ O,
                                             const bf16* __restrict__ WoT,
                                             float* __restrict__ out,
                                             const float* __restrict__ bo) {
  __shared__ __align__(16) bf16 As[8192];
  __shared__ __align__(16) bf16 Bs[8192];
  const int bid = blockIdx.x;
  const int s = (bid & 7) * 64 + (bid >> 3);   // XCD chunk-swizzle
  gemm_body<1>(O, WoT, 1024, (s >> 3) * 128, (s & 7) * 128, out, bo, As, Bs);
}

// ---------------- flash attention: LDS-free, barrier-free, L2-direct ----------------
// flat grid 1024, 256 threads = 4 waves; wave handles 32 q-rows.
// XCD swizzle keeps each (b,head)'s 256KB K/V slab on ONE XCD -> L2-resident, so
// MFMA fragments are read DIRECTLY from global each tile (Common-mistake #7 /
// m169: LDS-staging L2-fit data is pure overhead). No barriers at all: each wave
// is an independent dataflow (Kload -> QK -> Vload -> exp -> PV); TLP hides L2
// latency since waves are never phase-locked.
// S^T = K*Q^T puts keys in the register direction; V^T is sigma-permuted so the
// PV B-fragment is one contiguous 16B read. Wq carries the softmax scale.
// Row-sum l rides a ones-column MFMA (l = P @ 1) in the same layout as o.
__global__ __launch_bounds__(256) void attn_k(const bf16* __restrict__ Qg,
                                              const bf16* __restrict__ Kg,
                                              const bf16* __restrict__ VTg,
                                              bf16* __restrict__ Og) {
  const int tid = threadIdx.x;
  const int lane = tid & 63, w = tid >> 6;
  const int q = lane >> 4, c = lane & 15;
  const int bid = blockIdx.x;                          // 1024 flat
  const int pair = (bid & 7) * 8 + (bid >> 7);         // 0..63 ; 8 pairs per XCD
  const int head = pair & 15, b = pair >> 4;
  const int q0 = ((bid >> 3) & 15) * 128;

  bf16x8 aQ[2][2];
#pragma unroll
  for (int mj = 0; mj < 2; mj++)
#pragma unroll
    for (int ks = 0; ks < 2; ks++)
      aQ[mj][ks] = *(const bf16x8*)(Qg + (size_t)(b * 2048 + q0 + w * 32 + mj * 16 + c) * 1024 +
                                    head * 64 + ks * 32 + q * 8);

  f32x4 o[2][4] = {};
  f32x4 ol[2] = {};  // l via ones-MFMA: lane (q,c) reg r = l[qrow mi*16+q*4+r]
  bf16x8 vone;
#pragma unroll
  for (int i = 0; i < 8; i++) vone[i] = (bf16)1.0f;

  // per-lane fragment bases: K row = b*1024 + kt*64 + ni*16 + c, col head*64+ks*32+q*8
  //                          V row(d) = ni*16 + c, pkey = kt*64 + ks2*32 + q*8
  const bf16* Kf = Kg + (size_t)(b * 1024 + c) * 1024 + head * 64 + q * 8;
  const bf16* Vf = VTg + ((size_t)(b * 16 + head) * 64 + c) * 1024 + q * 8;

#pragma unroll 1
  for (int kt = 0; kt < 16; kt++) {
    const bf16* Kt = Kf + (size_t)kt * 65536;
    bf16x8 ak[2][4];
#pragma unroll
    for (int ks = 0; ks < 2; ks++)
#pragma unroll
      for (int ni = 0; ni < 4; ni++)
        ak[ks][ni] = *(const bf16x8*)(Kt + ni * 16384 + ks * 32);

    // S^T = K @ Q^T : lane (q,c) reg r of st[mj][ni] = S[qrow=mj*16+c][key=ni*16+q*4+r]
    f32x4 st[2][4] = {};
    __builtin_amdgcn_s_setprio(1);
#pragma unroll
    for (int ks = 0; ks < 2; ks++)
#pragma unroll
      for (int mj = 0; mj < 2; mj++)
#pragma unroll
        for (int ni = 0; ni < 4; ni++)
          st[mj][ni] = MFMA(ak[ks][ni], aQ[mj][ks], st[mj][ni]);
    __builtin_amdgcn_s_setprio(0);

    // issue V loads now; their L1/L2 latency hides under the exp phase
    const bf16* Vt2 = Vf + kt * 64;
    bf16x8 bv[2][4];
#pragma unroll
    for (int ks2 = 0; ks2 < 2; ks2++)
#pragma unroll
      for (int ni = 0; ni < 4; ni++)
        bv[ks2][ni] = *(const bf16x8*)(Vt2 + ni * 16384 + ks2 * 32);

    // p = exp2(s) (scale pre-folded into Wq); pack straight to bf16
    int pk[2][4][2];
#pragma unroll
    for (int mj = 0; mj < 2; mj++)
#pragma unroll
      for (int ni = 0; ni < 4; ni++) {
        float p0 = __builtin_amdgcn_exp2f(st[mj][ni][0]);
        float p1 = __builtin_amdgcn_exp2f(st[mj][ni][1]);
        float p2 = __builtin_amdgcn_exp2f(st[mj][ni][2]);
        float p3 = __builtin_amdgcn_exp2f(st[mj][ni][3]);
        HI h0, h1;
        h0.h[0] = (bf16)p0; h0.h[1] = (bf16)p1;
        h1.h[0] = (bf16)p2; h1.h[1] = (bf16)p3;
        pk[mj][ni][0] = h0.i;
        pk[mj][ni][1] = h1.i;
      }

    // O += P @ V in kappa key-order; sigma-permuted V^T makes B-frag one b128.
    // l += P @ 1 rides on the same A-fragment (permutation-invariant).
#pragma unroll
    for (int ks2 = 0; ks2 < 2; ks2++) {
#pragma unroll
      for (int mi = 0; mi < 2; mi++) {
        I4B8 pa;
        pa.i.x = pk[mi][2 * ks2][0];
        pa.i.y = pk[mi][2 * ks2][1];
        pa.i.z = pk[mi][2 * ks2 + 1][0];
        pa.i.w = pk[mi][2 * ks2 + 1][1];
        __builtin_amdgcn_s_setprio(1);
#pragma unroll
        for (int ni = 0; ni < 4; ni++)
          o[mi][ni] = MFMA(pa.v, bv[ks2][ni], o[mi][ni]);
        ol[mi] = MFMA(pa.v, vone, ol[mi]);
        __builtin_amdgcn_s_setprio(0);
      }
    }
  }

  // epilogue: ol[mi][r] is already l for qrow mi*16+q*4+r (every c holds a copy)
#pragma unroll
  for (int mi = 0; mi < 2; mi++) {
    float inv[4];
#pragma unroll
    for (int r = 0; r < 4; r++) inv[r] = 1.0f / ol[mi][r];
#pragma unroll
    for (int ni = 0; ni < 4; ni++)
#pragma unroll
      for (int r = 0; r < 4; r++) {
        const int qrow = q0 + w * 32 + mi * 16 + q * 4 + r;
        const int col = head * 64 + ni * 16 + c;
        Og[(size_t)(b * 2048 + qrow) * 1024 + col] = (bf16)(o[mi][ni][r] * inv[r]);
      }
  }
}

extern "C" void kernel_launch(void* const* d_in, const int* in_sizes, int n_in,
                              void* d_out, int out_size, void* d_ws, size_t ws_size,
                              hipStream_t stream) {
  (void)in_sizes; (void)n_in; (void)out_size; (void)ws_size;
  const float* x   = (const float*)d_in[0];
  const float* ctx = (const float*)d_in[1];
  const float* Wq  = (const float*)d_in[2];
  const float* Wk  = (const float*)d_in[3];
  const float* Wv  = (const float*)d_in[4];
  const float* Wo  = (const float*)d_in[5];
  const float* bo  = (const float*)d_in[6];
  float* out = (float*)d_out;

  char* ws = (char*)d_ws;
  const size_t MB = 1u << 20;
  bf16* WqT  = (bf16*)(ws);                 // 2 MiB   [1024][1024] (x 0.18033688)
  bf16* WkvT = (bf16*)(ws + 2 * MB);        // 3 MiB   [2048][768]
  bf16* WoT  = (bf16*)(ws + 5 * MB);        // 2 MiB
  bf16* ctxb = (bf16*)(ws + 7 * MB);        // 6 MiB   [4096][768]
  bf16* xb   = (bf16*)(ws + 13 * MB);       // 16 MiB  [8192][1024]; reused as O after Q-proj
  bf16* Q    = (bf16*)(ws + 29 * MB);       // 16 MiB
  bf16* Kp   = (bf16*)(ws + 45 * MB);       // 8 MiB
  bf16* VT   = (bf16*)(ws + 53 * MB);       // 8 MiB   [4][16][64][1024] sigma-permuted keys
  bf16* O    = xb;

  prep_k<<<5632 + 4096, 256, 0, stream>>>(x, xb, ctx, ctxb, Wq, WqT, Wk, WkvT, Wv, Wo, WoT);

  proj_k<<<1024, 256, 0, stream>>>(xb, ctxb, WqT, WkvT, Q, Kp, VT);

  attn_k<<<1024, 256, 0, stream>>>(Q, Kp, VT, O);

  out_k<<<512, 256, 0, stream>>>(O, WoT, out, bo);
}

// Round 3
// 205.145 us; speedup vs baseline: 1.5299x; 1.5299x over previous
//
#include <hip/hip_runtime.h>

typedef __bf16 bf16;
typedef __bf16 bf16x2 __attribute__((ext_vector_type(2)));
typedef __bf16 bf16x4 __attribute__((ext_vector_type(4)));
typedef __bf16 bf16x8 __attribute__((ext_vector_type(8)));
typedef float f32x4 __attribute__((ext_vector_type(4)));

#define MFMA(a, b, c) __builtin_amdgcn_mfma_f32_16x16x32_bf16(a, b, c, 0, 0, 0)

#define GLD16(gptr, ldsptr)                                                        \
  __builtin_amdgcn_global_load_lds(                                                \
      (const __attribute__((address_space(1))) unsigned int*)(gptr),               \
      (__attribute__((address_space(3))) unsigned int*)(ldsptr), 16, 0, 0)

union I4B8 { int4 i; bf16x8 v; };
union HI { bf16x2 h; int i; };

// ---------------- fused cast (x, ctx) + weight transposes, one dispatch ----------------
// Wq is additionally scaled by 0.125*log2(e) so attention can use raw exp2.
__global__ __launch_bounds__(256) void prep_k(const float* __restrict__ x, bf16* __restrict__ xb,
                                              const float* __restrict__ ctx, bf16* __restrict__ ctxb,
                                              const float* __restrict__ Wq, bf16* __restrict__ WqT,
                                              const float* __restrict__ Wk, bf16* __restrict__ WkvT,
                                              const float* __restrict__ Wv,
                                              const float* __restrict__ Wo, bf16* __restrict__ WoT) {
  __shared__ float t[32][33];
  const int bid = blockIdx.x;
  if (bid < 5632) {  // casts
    const float* in; bf16* out; size_t i;
    if (bid < 4096) { in = x; out = xb; i = ((size_t)bid * 256 + threadIdx.x) * 8; }
    else { in = ctx; out = ctxb; i = ((size_t)(bid - 4096) * 256 + threadIdx.x) * 8; }
    const float4 a = *(const float4*)(in + i);
    const float4 b = *(const float4*)(in + i + 4);
    bf16x8 o;
    o[0] = (bf16)a.x; o[1] = (bf16)a.y; o[2] = (bf16)a.z; o[3] = (bf16)a.w;
    o[4] = (bf16)b.x; o[5] = (bf16)b.y; o[6] = (bf16)b.z; o[7] = (bf16)b.w;
    *(bf16x8*)(out + i) = o;
    return;
  }
  // transposes: out[C][R] = (bf16)(in[R][C] * sc)
  const int tt = bid - 5632;
  const int z = tt >> 10, rem = tt & 1023;
  const float* in; bf16* out; int R; float sc = 1.0f;
  if (z == 0)      { in = Wq; out = WqT;                R = 1024; sc = 0.18033688f; }
  else if (z == 1) { in = Wk; out = WkvT;               R = 768; }
  else if (z == 2) { in = Wv; out = WkvT + 1024 * 768;  R = 768; }
  else             { in = Wo; out = WoT;                R = 1024; }
  const int c0 = (rem & 31) * 32, r0 = (rem >> 5) * 32;
  if (r0 >= R) return;
  const int tx = threadIdx.x & 31, ty = threadIdx.x >> 5;
#pragma unroll
  for (int i = 0; i < 4; i++)
    t[ty + i * 8][tx] = in[(size_t)(r0 + ty + i * 8) * 1024 + c0 + tx];
  __syncthreads();
#pragma unroll
  for (int i = 0; i < 4; i++)
    out[(size_t)(c0 + ty + i * 8) * R + r0 + tx] = (bf16)(t[tx][ty + i * 8] * sc);
}

// ---------------- GEMM body: C[M,N] = A[M,K] @ Bt[N,K]^T ----------------
// 128x128 tile, BK=64, XOR-swizzled LDS (elem col ^= (row&7)*8) so the 128B-stride
// ds_read_b128 is conflict-free. global_load_lds writes LINEARLY, so the swizzle is
// applied by pre-swizzling the per-lane GLOBAL source column (both-sides-or-neither).
// MODE 0: SWAPPED (C^T frags) -> bf16 rowmajor ld=1024, b64 stores.
// MODE 1: SWAPPED -> fp32 rowmajor ld=1024 + bias, dwordx4 stores.
// MODE 2: NORMAL  -> V^T [B,H,64,1024] with sigma key-permute, b64 stores.
template <int MODE>
__device__ __forceinline__ void gemm_body(const bf16* __restrict__ A,
                                          const bf16* __restrict__ Bt,
                                          int K, int m0, int n0,
                                          void* __restrict__ C0,
                                          const float* __restrict__ bias,
                                          bf16* As, bf16* Bs) {
  const int tid = threadIdx.x;
  const int lane = tid & 63, wave = tid >> 6;
  const int wm = wave >> 1, wn = wave & 1;
  const int q = lane >> 4, c = lane & 15;

  f32x4 acc[4][4] = {};
  // staging: thread t -> row r = t>>3 (+32 per call), 16B at swizzled col
  const int r = tid >> 3;
  const int col8 = ((tid & 7) * 8) ^ ((r & 7) * 8);
  const bf16* Ag = A + (size_t)(m0 + r) * K + col8;
  const bf16* Bg = Bt + (size_t)(n0 + r) * K + col8;
  const size_t K32 = (size_t)K * 32;
  bf16* AsW = As + wave * 512;   // call j writes As + j*2048 + wave*512
  bf16* BsW = Bs + wave * 512;
  const int swz = (c & 7) * 8;   // read-side XOR (row&7 == c&7 for frag rows)

  for (int k0 = 0; k0 < K; k0 += 64) {
    __syncthreads();
    GLD16(Ag + k0,            AsW);
    GLD16(Ag + k0 + K32,      AsW + 2048);
    GLD16(Ag + k0 + 2 * K32,  AsW + 4096);
    GLD16(Ag + k0 + 3 * K32,  AsW + 6144);
    GLD16(Bg + k0,            BsW);
    GLD16(Bg + k0 + K32,      BsW + 2048);
    GLD16(Bg + k0 + 2 * K32,  BsW + 4096);
    GLD16(Bg + k0 + 3 * K32,  BsW + 6144);
    __syncthreads();
#pragma unroll
    for (int kk = 0; kk < 2; kk++) {
      const int cx = (kk * 32 + q * 8) ^ swz;
      bf16x8 af[4], bfr[4];
#pragma unroll
      for (int mi = 0; mi < 4; mi++)
        af[mi] = *(const bf16x8*)&As[(wm * 64 + mi * 16 + c) * 64 + cx];
#pragma unroll
      for (int ni = 0; ni < 4; ni++)
        bfr[ni] = *(const bf16x8*)&Bs[(wn * 64 + ni * 16 + c) * 64 + cx];
      __builtin_amdgcn_s_setprio(1);
#pragma unroll
      for (int mi = 0; mi < 4; mi++)
#pragma unroll
        for (int ni = 0; ni < 4; ni++) {
          if constexpr (MODE == 2)
            acc[mi][ni] = MFMA(af[mi], bfr[ni], acc[mi][ni]);   // D[m][n]
          else
            acc[mi][ni] = MFMA(bfr[ni], af[mi], acc[mi][ni]);   // D[n][m]
        }
      __builtin_amdgcn_s_setprio(0);
    }
  }

  if constexpr (MODE == 0 || MODE == 1) {
    // swapped: lane (q,c) of acc[mi][ni] holds row m0+wm*64+mi*16+c,
    // cols n0+wn*64+ni*16+q*4 .. +3
#pragma unroll
    for (int ni = 0; ni < 4; ni++) {
      const int col = n0 + wn * 64 + ni * 16 + q * 4;
      float4 bv4 = {};
      if constexpr (MODE == 1) bv4 = *(const float4*)&bias[col];
#pragma unroll
      for (int mi = 0; mi < 4; mi++) {
        const int row = m0 + wm * 64 + mi * 16 + c;
        if constexpr (MODE == 0) {
          bf16x4 vv;
#pragma unroll
          for (int r2 = 0; r2 < 4; r2++) vv[r2] = (bf16)acc[mi][ni][r2];
          *(bf16x4*)&((bf16*)C0)[(size_t)row * 1024 + col] = vv;
        } else {
          f32x4 vv;
          vv[0] = acc[mi][ni][0] + bv4.x; vv[1] = acc[mi][ni][1] + bv4.y;
          vv[2] = acc[mi][ni][2] + bv4.z; vv[3] = acc[mi][ni][3] + bv4.w;
          *(f32x4*)&((float*)C0)[(size_t)row * 1024 + col] = vv;
        }
      }
    }
  } else {
    // normal: lane (q,c) of acc[mi][ni] holds rows rbase+q*4..+3 (keys), col fixed.
#pragma unroll
    for (int ni = 0; ni < 4; ni++) {
      const int col = n0 + wn * 64 + ni * 16 + c;
#pragma unroll
      for (int mi = 0; mi < 4; mi++) {
        const int rbase = m0 + wm * 64 + mi * 16 + q * 4;
        const int b = rbase >> 10, key = rbase & 1023;
        bf16* VT = (bf16*)C0;
        const int h = col >> 6, d = col & 63;
        const int kl = key & 63;
        const int pkey = (key & ~63) | (kl & 32) | ((kl & 12) << 1) | ((kl & 16) >> 2);
        bf16x4 vv;
#pragma unroll
        for (int r2 = 0; r2 < 4; r2++) vv[r2] = (bf16)acc[mi][ni][r2];
        *(bf16x4*)&VT[((size_t)(b * 16 + h) * 64 + d) * 1024 + pkey] = vv;
      }
    }
  }
}

// ---------------- fused Q-proj + K-proj + V-proj, 1024 blocks ----------------
// XCD chunk-swizzle per segment: each XCD owns a contiguous band of row-tiles.
__global__ __launch_bounds__(256) void proj_k(const bf16* __restrict__ xb,
                                              const bf16* __restrict__ ctxb,
                                              const bf16* __restrict__ WqT,
                                              const bf16* __restrict__ WkvT,
                                              bf16* __restrict__ Q,
                                              bf16* __restrict__ Kp,
                                              bf16* __restrict__ VT) {
  __shared__ __align__(16) bf16 As[8192];
  __shared__ __align__(16) bf16 Bs[8192];
  const int bid = blockIdx.x;
  if (bid < 512) {        // Q projection: M=8192, N=1024, K=1024, bf16 swapped
    const int s = (bid & 7) * 64 + (bid >> 3);
    gemm_body<0>(xb, WqT, 1024, (s >> 3) * 128, (s & 7) * 128, Q, nullptr, As, Bs);
  } else if (bid < 768) { // K projection: M=4096, N=1024, K=768, bf16 swapped
    const int t = bid - 512;
    const int s = (t & 7) * 32 + (t >> 3);
    gemm_body<0>(ctxb, WkvT, 768, (s >> 3) * 128, (s & 7) * 128, Kp, nullptr, As, Bs);
  } else {                // V projection: M=4096, N=1024, K=768, normal -> sigma V^T
    const int t = bid - 768;
    const int s = (t & 7) * 32 + (t >> 3);
    gemm_body<2>(ctxb, WkvT + (size_t)1024 * 768, 768, (s >> 3) * 128, (s & 7) * 128,
                 VT, nullptr, As, Bs);
  }
}

// ---------------- output projection, fp32 + bias, 128x128 tiles (512 blocks) ----------------
__global__ __launch_bounds__(256) void out_k(const bf16* __restrict__ O,
                                             const bf16* __restrict__ WoT,
                                             float* __restrict__ out,
                                             const float* __restrict__ bo) {
  __shared__ __align__(16) bf16 As[8192];
  __shared__ __align__(16) bf16 Bs[8192];
  const int bid = blockIdx.x;
  const int s = (bid & 7) * 64 + (bid >> 3);   // XCD chunk-swizzle
  gemm_body<1>(O, WoT, 1024, (s >> 3) * 128, (s & 7) * 128, out, bo, As, Bs);
}

// ---------------- flash attention: S^T trick + permuted-key PV + reg prefetch ----------------
// 512 blocks, 256 threads = 4 waves; wave handles 64 q-rows (mj=0..3).
// Doubling q-rows/wave halves the per-CU LDS read traffic (each K/V fragment read
// feeds 4 MFMAs instead of 2) and halves total K/V staging traffic. VGPR ~220 ->
// __launch_bounds__(256,2) keeps 2 waves/SIMD resident without spilling.
// XCD swizzle: the 8 q-tile blocks of one (b,head) pair land on ONE XCD (8 pairs
// x 256KB K/V = 2MB per XCD L2). S^T = K*Q^T puts keys in the register direction;
// V^T is sigma-permuted so the PV B-fragment is one b128. Tile kt+1 is prefetched
// into registers before computing tile kt. Wq carries the softmax scale -> exp2.
// Row-sum l rides a ones-column MFMA (l = P @ 1) in the same layout as o.
__global__ __launch_bounds__(256, 2) void attn_k(const bf16* __restrict__ Qg,
                                                 const bf16* __restrict__ Kg,
                                                 const bf16* __restrict__ VTg,
                                                 bf16* __restrict__ Og) {
  __shared__ __align__(16) bf16 Ks[64][72];  // [key][d]
  __shared__ __align__(16) bf16 Vt[64][72];  // [d][physkey]
  const int tid = threadIdx.x;
  const int lane = tid & 63, w = tid >> 6;
  const int q = lane >> 4, c = lane & 15;
  const int bid = blockIdx.x;                  // 512 flat
  const int pair = (bid & 7) * 8 + (bid >> 6); // 0..63 ; 8 pairs per XCD
  const int head = pair & 15, b = pair >> 4;
  const int q0 = ((bid >> 3) & 7) * 256;

  bf16x8 aQ[4][2];
#pragma unroll
  for (int mj = 0; mj < 4; mj++)
#pragma unroll
    for (int ks = 0; ks < 2; ks++)
      aQ[mj][ks] = *(const bf16x8*)(Qg + (size_t)(b * 2048 + q0 + w * 64 + mj * 16 + c) * 1024 +
                                    head * 64 + ks * 32 + q * 8);

  f32x4 o[4][4] = {};
  f32x4 ol[4] = {};  // l via ones-MFMA: lane (q,c) reg r = l[qrow mi*16+q*4+r]
  bf16x8 vone;
#pragma unroll
  for (int i = 0; i < 8; i++) vone[i] = (bf16)1.0f;

  const int srow = tid >> 2, sc = tid & 3;
  const bf16* Kbase = Kg + (size_t)(b * 1024 + srow) * 1024 + head * 64 + sc * 16;
  const bf16* Vbase = VTg + ((size_t)(b * 16 + head) * 64 + srow) * 1024 + sc * 16;

  // prefetch tile 0 into registers
  bf16x8 rk0 = *(const bf16x8*)(Kbase);
  bf16x8 rk1 = *(const bf16x8*)(Kbase + 8);
  bf16x8 rv0 = *(const bf16x8*)(Vbase);
  bf16x8 rv1 = *(const bf16x8*)(Vbase + 8);

  for (int kt = 0; kt < 16; kt++) {
    __syncthreads();  // prior tile's LDS readers done
    *(bf16x8*)&Ks[srow][sc * 16]     = rk0;
    *(bf16x8*)&Ks[srow][sc * 16 + 8] = rk1;
    *(bf16x8*)&Vt[srow][sc * 16]     = rv0;
    *(bf16x8*)&Vt[srow][sc * 16 + 8] = rv1;
    if (kt < 15) {  // issue next tile's loads; they land during this tile's compute
      const size_t ko = (size_t)(kt + 1) * 64 * 1024;
      const int vo = (kt + 1) * 64;
      rk0 = *(const bf16x8*)(Kbase + ko);
      rk1 = *(const bf16x8*)(Kbase + ko + 8);
      rv0 = *(const bf16x8*)(Vbase + vo);
      rv1 = *(const bf16x8*)(Vbase + vo + 8);
    }
    __syncthreads();  // staging writes visible

    // S^T = K @ Q^T : lane (q,c) reg r of st[mj][ni] = S[qrow=mj*16+c][key=ni*16+q*4+r]
    f32x4 st[4][4] = {};
#pragma unroll
    for (int ks = 0; ks < 2; ks++) {
      bf16x8 ak[4];
#pragma unroll
      for (int ni = 0; ni < 4; ni++) ak[ni] = *(const bf16x8*)&Ks[ni * 16 + c][ks * 32 + q * 8];
      __builtin_amdgcn_s_setprio(1);
#pragma unroll
      for (int mj = 0; mj < 4; mj++)
#pragma unroll
        for (int ni = 0; ni < 4; ni++)
          st[mj][ni] = MFMA(ak[ni], aQ[mj][ks], st[mj][ni]);
      __builtin_amdgcn_s_setprio(0);
    }

    // p = exp2(s) (scale pre-folded into Wq); pack straight to bf16
    int pk[4][4][2];
#pragma unroll
    for (int mj = 0; mj < 4; mj++)
#pragma unroll
      for (int ni = 0; ni < 4; ni++) {
        float p0 = __builtin_amdgcn_exp2f(st[mj][ni][0]);
        float p1 = __builtin_amdgcn_exp2f(st[mj][ni][1]);
        float p2 = __builtin_amdgcn_exp2f(st[mj][ni][2]);
        float p3 = __builtin_amdgcn_exp2f(st[mj][ni][3]);
        HI h0, h1;
        h0.h[0] = (bf16)p0; h0.h[1] = (bf16)p1;
        h1.h[0] = (bf16)p2; h1.h[1] = (bf16)p3;
        pk[mj][ni][0] = h0.i;
        pk[mj][ni][1] = h1.i;
      }

    // O += P @ V in kappa key-order; sigma-permuted Vt makes B-frag one b128.
    // l += P @ 1 rides on the same A-fragment (permutation-invariant).
#pragma unroll
    for (int ks2 = 0; ks2 < 2; ks2++) {
      bf16x8 bv[4];
#pragma unroll
      for (int ni = 0; ni < 4; ni++)
        bv[ni] = *(const bf16x8*)&Vt[ni * 16 + c][ks2 * 32 + q * 8];
#pragma unroll
      for (int mi = 0; mi < 4; mi++) {
        I4B8 pa;
        pa.i.x = pk[mi][2 * ks2][0];
        pa.i.y = pk[mi][2 * ks2][1];
        pa.i.z = pk[mi][2 * ks2 + 1][0];
        pa.i.w = pk[mi][2 * ks2 + 1][1];
        __builtin_amdgcn_s_setprio(1);
#pragma unroll
        for (int ni = 0; ni < 4; ni++)
          o[mi][ni] = MFMA(pa.v, bv[ni], o[mi][ni]);
        ol[mi] = MFMA(pa.v, vone, ol[mi]);
        __builtin_amdgcn_s_setprio(0);
      }
    }
  }

  // epilogue: ol[mi][r] is already l for qrow mi*16+q*4+r (every c holds a copy)
#pragma unroll
  for (int mi = 0; mi < 4; mi++) {
    float inv[4];
#pragma unroll
    for (int r = 0; r < 4; r++) inv[r] = 1.0f / ol[mi][r];
#pragma unroll
    for (int ni = 0; ni < 4; ni++)
#pragma unroll
      for (int r = 0; r < 4; r++) {
        const int qrow = q0 + w * 64 + mi * 16 + q * 4 + r;
        const int col = head * 64 + ni * 16 + c;
        Og[(size_t)(b * 2048 + qrow) * 1024 + col] = (bf16)(o[mi][ni][r] * inv[r]);
      }
  }
}

extern "C" void kernel_launch(void* const* d_in, const int* in_sizes, int n_in,
                              void* d_out, int out_size, void* d_ws, size_t ws_size,
                              hipStream_t stream) {
  (void)in_sizes; (void)n_in; (void)out_size; (void)ws_size;
  const float* x   = (const float*)d_in[0];
  const float* ctx = (const float*)d_in[1];
  const float* Wq  = (const float*)d_in[2];
  const float* Wk  = (const float*)d_in[3];
  const float* Wv  = (const float*)d_in[4];
  const float* Wo  = (const float*)d_in[5];
  const float* bo  = (const float*)d_in[6];
  float* out = (float*)d_out;

  char* ws = (char*)d_ws;
  const size_t MB = 1u << 20;
  bf16* WqT  = (bf16*)(ws);                 // 2 MiB   [1024][1024] (x 0.18033688)
  bf16* WkvT = (bf16*)(ws + 2 * MB);        // 3 MiB   [2048][768]
  bf16* WoT  = (bf16*)(ws + 5 * MB);        // 2 MiB
  bf16* ctxb = (bf16*)(ws + 7 * MB);        // 6 MiB   [4096][768]
  bf16* xb   = (bf16*)(ws + 13 * MB);       // 16 MiB  [8192][1024]; reused as O after Q-proj
  bf16* Q    = (bf16*)(ws + 29 * MB);       // 16 MiB
  bf16* Kp   = (bf16*)(ws + 45 * MB);       // 8 MiB
  bf16* VT   = (bf16*)(ws + 53 * MB);       // 8 MiB   [4][16][64][1024] sigma-permuted keys
  bf16* O    = xb;

  prep_k<<<5632 + 4096, 256, 0, stream>>>(x, xb, ctx, ctxb, Wq, WqT, Wk, WkvT, Wv, Wo, WoT);

  proj_k<<<1024, 256, 0, stream>>>(xb, ctxb, WqT, WkvT, Q, Kp, VT);

  attn_k<<<512, 256, 0, stream>>>(Q, Kp, VT, O);

  out_k<<<512, 256, 0, stream>>>(O, WoT, out, bo);
}